// Round 1
// 555.680 us; speedup vs baseline: 1.0321x; 1.0321x over previous
//
#include <hip/hip_runtime.h>
#include <hip/hip_bf16.h>

typedef __hip_bfloat16 hbf16;
typedef __bf16 bf16x8 __attribute__((ext_vector_type(8)));
typedef float f32x4 __attribute__((ext_vector_type(4)));

#define MFMA16(a, b, c) __builtin_amdgcn_mfma_f32_16x16x32_bf16((a), (b), (c), 0, 0, 0)

// async global->LDS, 16B per lane. LDS dest = wave-uniform base + lane*16.
#define ASYNC16(ldsaddr, gaddr)                                                        \
  __builtin_amdgcn_global_load_lds(                                                    \
      (__attribute__((address_space(1))) void*)(void*)(gaddr),                         \
      (__attribute__((address_space(3))) void*)(ldsaddr), 16, 0, 0)

static __device__ __forceinline__ float fexp2(float x) {
#if __has_builtin(__builtin_amdgcn_exp2f)
  return __builtin_amdgcn_exp2f(x);
#else
  return exp2f(x);
#endif
}

// ---------------------------------------------------------------- quantization
// grid (512, 4): x = group(64) x split(8); y = matrix {wq,wk,wv,wo}.
// Each block writes its own (slot,split) cell -> no init, no atomics.
__global__ void quant_max_kernel(const float* __restrict__ wq, const float* __restrict__ wk,
                                 const float* __restrict__ wv, const float* __restrict__ wo,
                                 unsigned int* __restrict__ gmaxs) {
  const int my = blockIdx.y;
  const float* W;
  int slotBase, rowsPerSplit;
  if (my == 0) { W = wq; slotBase = 0;   rowsPerSplit = 512; }
  else if (my == 1) { W = wk; slotBase = 64;  rowsPerSplit = 128; }
  else if (my == 2) { W = wv; slotBase = 128; rowsPerSplit = 128; }
  else { W = wo; slotBase = 192; rowsPerSplit = 512; }
  const int tid = threadIdx.x;
  const int group = blockIdx.x & 63;
  const int split = blockIdx.x >> 6;
  const int c4 = (tid & 15) * 4;
  const int rs = tid >> 4;  // 0..15
  const float* base = W + (size_t)(split * rowsPerSplit) * 4096 + group * 64 + c4;
  float m = 0.f;
  for (int r = rs; r < rowsPerSplit; r += 16) {
    float4 v = *(const float4*)(base + (size_t)r * 4096);
    m = fmaxf(m, fmaxf(fmaxf(fabsf(v.x), fabsf(v.y)), fmaxf(fabsf(v.z), fabsf(v.w))));
  }
  for (int d = 1; d < 64; d <<= 1) m = fmaxf(m, __shfl_xor(m, d, 64));
  __shared__ float wm_[4];
  if ((tid & 63) == 0) wm_[tid >> 6] = m;
  __syncthreads();
  if (tid == 0) {
    m = fmaxf(fmaxf(wm_[0], wm_[1]), fmaxf(wm_[2], wm_[3]));
    gmaxs[(slotBase + group) * 8 + split] = __float_as_uint(m);
  }
}

// w_q = trunc(w * 2^(7-gex)) * 2^(gex-7), exact in bf16.
// blockbase/stride passed explicitly so this can be embedded in fused dispatches.
// Requires stride % 1024 == 0 (group invariant across iterations).
__device__ __forceinline__ void quant_body(const float* __restrict__ W, hbf16* __restrict__ Wq,
                                           const unsigned int* __restrict__ gmaxs, int slotBase,
                                           int n4, int block0, int nblocks) {
  const int stride = nblocks * 256;
  const int idx0 = block0 * 256 + (int)threadIdx.x;
  if (idx0 >= n4) return;
  const int slot = slotBase + ((idx0 & 1023) >> 4);
  unsigned int mb = 0;
#pragma unroll
  for (int sp = 0; sp < 8; ++sp) mb = max(mb, gmaxs[slot * 8 + sp]);
  int gex = (int)((mb >> 23) & 255) - 127;
  float s = __uint_as_float((unsigned)(134 - gex) << 23);    // 2^(7-gex)
  float inv = __uint_as_float((unsigned)(120 + gex) << 23);  // 2^(gex-7)
  for (int idx = idx0; idx < n4; idx += stride) {
    float4 w = *(const float4*)(W + (size_t)idx * 4);
    hbf16 t[4];
    t[0] = __float2bfloat16(truncf(w.x * s) * inv);
    t[1] = __float2bfloat16(truncf(w.y * s) * inv);
    t[2] = __float2bfloat16(truncf(w.z * s) * inv);
    t[3] = __float2bfloat16(truncf(w.w * s) * inv);
    *(uint2*)(Wq + (size_t)idx * 4) = *(uint2*)t;
  }
}

// grid (2048, 4): y=0 wq, y=1 wk, y=2 wv (into stacked wqkv), y=3 x->bf16
__global__ void prep_kernel(const float* __restrict__ wq, const float* __restrict__ wk,
                            const float* __restrict__ wv, const float* __restrict__ x,
                            hbf16* __restrict__ Wqkv, hbf16* __restrict__ xb,
                            const unsigned int* __restrict__ gmaxs) {
  const int my = blockIdx.y;
  if (my == 0) {
    quant_body(wq, Wqkv, gmaxs, 0, 4096 * 4096 / 4, blockIdx.x, gridDim.x);
  } else if (my == 1) {
    quant_body(wk, Wqkv + (size_t)4096 * 4096, gmaxs, 64, 1024 * 4096 / 4, blockIdx.x, gridDim.x);
  } else if (my == 2) {
    quant_body(wv, Wqkv + (size_t)5120 * 4096, gmaxs, 128, 1024 * 4096 / 4, blockIdx.x, gridDim.x);
  } else {
    const int stride = gridDim.x * 256;
    for (int idx = blockIdx.x * 256 + threadIdx.x; idx < 2048 * 4096 / 4; idx += stride) {
      float4 v = *(const float4*)(x + (size_t)idx * 4);
      hbf16 t[4] = {__float2bfloat16(v.x), __float2bfloat16(v.y),
                    __float2bfloat16(v.z), __float2bfloat16(v.w)};
      *(uint2*)(xb + (size_t)idx * 4) = *(uint2*)t;
    }
  }
}

// --------------------------------------------- post-QKV fused dispatch
// blocks [0,2048): wo quant; [2048,18432): rope Q; [18432,22528): rope K;
// [22528,23040): V transpose.  All depend only on the QKV GEMM.
__global__ void postproc_kernel(const float* __restrict__ wo, hbf16* __restrict__ woq,
                                const unsigned int* __restrict__ gmaxs,
                                const float* __restrict__ qkv, const float* __restrict__ Cs,
                                const float* __restrict__ Sn, hbf16* __restrict__ qrope,
                                hbf16* __restrict__ krope, hbf16* __restrict__ Vt, float qscale) {
  __shared__ float tile[64][65];
  const int bid = blockIdx.x;
  const int tid = threadIdx.x;
  if (bid < 2048) {
    quant_body(wo, woq, gmaxs, 192, 4096 * 4096 / 4, bid, 2048);
  } else if (bid < 18432) {
    // rope Q: 2048 pairs/row, stride 6144, scale folded
    int i = (bid - 2048) * 256 + tid;
    int s = i >> 11, p = i & 2047, t = p & 63;
    float2 q = *(const float2*)(qkv + (size_t)s * 6144 + p * 2);
    float c = Cs[s * 64 + t] * qscale, sn = Sn[s * 64 + t] * qscale;
    hbf16 o[2] = {__float2bfloat16(q.x * c - q.y * sn), __float2bfloat16(q.x * sn + q.y * c)};
    *(unsigned int*)(qrope + (size_t)s * 4096 + p * 2) = *(unsigned int*)o;
  } else if (bid < 22528) {
    // rope K: 512 pairs/row at col offset 4096
    int i = (bid - 18432) * 256 + tid;
    int s = i >> 9, p = i & 511, t = p & 63;
    float2 q = *(const float2*)(qkv + (size_t)s * 6144 + 4096 + p * 2);
    float c = Cs[s * 64 + t], sn = Sn[s * 64 + t];
    hbf16 o[2] = {__float2bfloat16(q.x * c - q.y * sn), __float2bfloat16(q.x * sn + q.y * c)};
    *(unsigned int*)(krope + (size_t)s * 1024 + p * 2) = *(unsigned int*)o;
  } else {
    // V transpose: qkv[s][5120+g*128+d] -> Vt[g][d][s]
    int id = bid - 22528;
    int g = id & 7, sb = (id >> 3) & 31, db = id >> 8;
    int c = tid & 63;
    for (int r = tid >> 6; r < 64; r += 4)
      tile[r][c] = qkv[(size_t)(sb * 64 + r) * 6144 + 5120 + g * 128 + db * 64 + c];
    __syncthreads();
    for (int r = tid >> 6; r < 64; r += 4)
      Vt[(size_t)g * 262144 + (size_t)(db * 64 + r) * 2048 + sb * 64 + c] =
          __float2bfloat16(tile[c][r]);
  }
}

// ------------------------------------------------------------------ GEMM C=A*Bt^T
// 128x256 tile, BK=64, 8 waves (2M x 4N), per-wave 64x64 output.
// Triple-buffered LDS (prefetch 2 K-tiles ahead) + counted vmcnt (never 0 in the
// main loop) + raw s_barrier phases + setprio around MFMA clusters (T3+T4+T5).
// LDS chunk swizzle: 16B chunk c of row r stored at c^(r&7) (T2; conflict-free).
//
// Race-freedom invariants:
//   tile t reads  buf[t%3]; stages during tile t write buf[(t+2)%3] only.
//   buf[(t+1)%3] (in flight) is neither read nor written during tile t.
//   arrival: vmcnt(6) at end of tile t-1 retires everything except tile t+1's
//   6 loads => tile t's 6 loads (issued at t-2) have landed; the following
//   s_barrier makes that true for all 8 waves before any phase-0 ds_read.
__global__ __launch_bounds__(512, 2) void gemm8_kernel(const hbf16* __restrict__ A,
                                                       const hbf16* __restrict__ Bt,
                                                       float* __restrict__ C, int N) {
  constexpr int K = 4096;
  constexpr int NT = K / 64;                      // 64 K-tiles
  constexpr int TILE = 128 * 128 + 256 * 128;     // A(16KB) + B(32KB) bytes
  __shared__ __align__(16) char smem[3 * TILE];
  const int tid = threadIdx.x;
  const int wave = tid >> 6, lane = tid & 63;
  const int l15 = lane & 15, quad = lane >> 4;
  const int bm = blockIdx.x, bn = blockIdx.y;
  const int wm = (wave >> 2) * 64, wn = (wave & 3) * 64;

  const char* Ab = (const char*)(A + (size_t)bm * 128 * K);
  const char* Bb = (const char*)(Bt + (size_t)bn * 256 * K);

  f32x4 acc[4][4];
#pragma unroll
  for (int i = 0; i < 4; ++i)
#pragma unroll
    for (int n = 0; n < 4; ++n) acc[i][n] = (f32x4){0.f, 0.f, 0.f, 0.f};

  // 2 insts/thread: A half (128 rows x 128B)
  auto stageA = [&](char* buf, int kk) {
#pragma unroll
    for (int r = 0; r < 2; ++r) {
      int f = r * 8192 + tid * 16;
      int row = f >> 7;
      int lc = ((f >> 4) & 7) ^ (row & 7);
      ASYNC16(buf + f, Ab + (size_t)row * (K * 2) + kk * 2 + lc * 16);
    }
  };
  // 4 insts/thread: B (256 rows x 128B)
  auto stageB = [&](char* buf, int kk) {
#pragma unroll
    for (int r = 0; r < 4; ++r) {
      int f = r * 8192 + tid * 16;
      int row = f >> 7;
      int lc = ((f >> 4) & 7) ^ (row & 7);
      ASYNC16(buf + 16384 + f, Bb + (size_t)row * (K * 2) + kk * 2 + lc * 16);
    }
  };

  // prologue: tiles 0 and 1 in flight; wait for tile 0 (6 = tile 1's loads).
  stageA(smem, 0);
  stageB(smem, 0);
  stageA(smem + TILE, 64);
  stageB(smem + TILE, 64);
  asm volatile("s_waitcnt vmcnt(6)" ::: "memory");
  __builtin_amdgcn_s_barrier();

  int cur = 0;
  for (int t = 0; t < NT; ++t) {
    const char* sa = smem + cur * TILE;
    const char* sb = sa + 16384;
    const int nxt2 = (cur >= 1) ? cur - 1 : 2;  // (cur+2)%3
    char* stg = smem + nxt2 * TILE;
    const int kk2 = ((t + 2 < NT) ? t + 2 : NT - 1) * 64;  // clamped dummy at tail

    // ---- phase 0: all A-frags + B-frags n=0,1 ; stage next2 A-half
    bf16x8 af[2][4], b0[2][2];
#pragma unroll
    for (int kc = 0; kc < 2; ++kc) {
      const int cx = (((kc << 2) | quad) ^ (l15 & 7)) * 16;
#pragma unroll
      for (int i = 0; i < 4; ++i)
        af[kc][i] = *(const bf16x8*)(sa + (wm + i * 16 + l15) * 128 + cx);
#pragma unroll
      for (int n = 0; n < 2; ++n)
        b0[kc][n] = *(const bf16x8*)(sb + (wn + n * 16 + l15) * 128 + cx);
    }
    stageA(stg, kk2);
    __builtin_amdgcn_s_barrier();
    __builtin_amdgcn_s_setprio(1);
#pragma unroll
    for (int kc = 0; kc < 2; ++kc)
#pragma unroll
      for (int i = 0; i < 4; ++i)
#pragma unroll
        for (int n = 0; n < 2; ++n) acc[i][n] = MFMA16(af[kc][i], b0[kc][n], acc[i][n]);
    __builtin_amdgcn_s_setprio(0);
    __builtin_amdgcn_s_barrier();

    // ---- phase 1: B-frags n=2,3 (A reused from regs); stage next2 B; counted wait
    bf16x8 b1[2][2];
#pragma unroll
    for (int kc = 0; kc < 2; ++kc) {
      const int cx = (((kc << 2) | quad) ^ (l15 & 7)) * 16;
#pragma unroll
      for (int n = 0; n < 2; ++n)
        b1[kc][n] = *(const bf16x8*)(sb + (wn + (n + 2) * 16 + l15) * 128 + cx);
    }
    stageB(stg, kk2);
    asm volatile("s_waitcnt vmcnt(6)" ::: "memory");
    __builtin_amdgcn_s_barrier();
    __builtin_amdgcn_s_setprio(1);
#pragma unroll
    for (int kc = 0; kc < 2; ++kc)
#pragma unroll
      for (int i = 0; i < 4; ++i)
#pragma unroll
        for (int n = 0; n < 2; ++n)
          acc[i][n + 2] = MFMA16(af[kc][i], b1[kc][n], acc[i][n + 2]);
    __builtin_amdgcn_s_setprio(0);
    __builtin_amdgcn_s_barrier();

    cur = (cur == 2) ? 0 : cur + 1;
  }

#pragma unroll
  for (int i = 0; i < 4; ++i) {
    int row = bm * 128 + wm + i * 16 + quad * 4;
#pragma unroll
    for (int n = 0; n < 4; ++n) {
      float* cp = C + (size_t)row * N + bn * 256 + wn + n * 16 + l15;
#pragma unroll
      for (int r = 0; r < 4; ++r) cp[(size_t)r * N] = acc[i][n][r];
    }
  }
}

// ------------------------------------------------------------- flash attention
// S^T formulation: S^T = K·Q^T (C col = qrow -> per-lane scalar softmax state),
// O^T = V^T·P^T with P^T's B-fragment built in-register via shuffles.
// Softmax scale pre-folded into Q. Masking only on the diagonal K-tile.
__global__ __launch_bounds__(256, 4) void attn_kernel(const hbf16* __restrict__ Q,
                                                      const hbf16* __restrict__ Kr,
                                                      const hbf16* __restrict__ Vt,
                                                      hbf16* __restrict__ O) {
  __shared__ __align__(16) hbf16 sK[64 * 128];  // [key][d], chunk^(key&15) swizzle
  __shared__ __align__(16) hbf16 sV[128 * 64];  // [d][key], chunk^(d&7) swizzle
  const int tid = threadIdx.x;
  const int wave = tid >> 6, lane = tid & 63;
  const int l15 = lane & 15, quad = lane >> 4;
  const int bid = blockIdx.x;
  const int h = bid >> 5;
  // per-CU balance: blocks {t,t+256,t+512,t+768} land on one CU and get qb
  // offsets {0,8,16,24} -> per-CU tile sum in [52,80] vs mean 66.
  const int qb = (31 - (bid & 31) + 8 * ((bid >> 8) & 3)) & 31;
  const int g = h >> 2;
  const int qrow0 = qb * 64 + wave * 16;
  const int qrow = qrow0 + l15;  // this lane's query row (S^T col)

  bf16x8 qf[4];
  {
    const hbf16* qp = Q + (size_t)qrow * 4096 + h * 128 + quad * 8;
#pragma unroll
    for (int kc = 0; kc < 4; ++kc) qf[kc] = *(const bf16x8*)(qp + kc * 32);
  }
  f32x4 of[8];
#pragma unroll
  for (int nf = 0; nf < 8; ++nf) of[nf] = (f32x4){0.f, 0.f, 0.f, 0.f};
  float m_i = -1e30f, l_i = 0.f;

  const char* Kb = (const char*)Kr + (size_t)g * 256;     // + key*2048 + d*2
  const char* Vb = (const char*)Vt + (size_t)g * 524288;  // + d*4096 + key*2
  char* sKb = (char*)sK;
  char* sVb = (char*)sV;

  const int nkb = qb + 1;
  for (int kb = 0; kb < nkb; ++kb) {
#pragma unroll
    for (int r = 0; r < 4; ++r) {
      int f = r * 4096 + tid * 16;
      {
        int row = f >> 8;                       // K: 64 keys x 256B
        int lc = ((f >> 4) & 15) ^ (row & 15);  // logical d-chunk
        ASYNC16(sKb + f, Kb + (size_t)(kb * 64 + row) * 2048 + lc * 16);
      }
      {
        int row = f >> 7;                     // Vt: 128 d x 128B
        int lc = ((f >> 4) & 7) ^ (row & 7);  // logical key-chunk
        ASYNC16(sVb + f, Vb + (size_t)row * 4096 + kb * 128 + lc * 16);
      }
    }
    __syncthreads();

    // S^T tiles: sacc[n] holds S^T[key = n*16 + quad*4 + r][qrow]
    f32x4 sacc[4];
#pragma unroll
    for (int n = 0; n < 4; ++n) sacc[n] = (f32x4){0.f, 0.f, 0.f, 0.f};
#pragma unroll
    for (int n = 0; n < 4; ++n)
#pragma unroll
      for (int kc = 0; kc < 4; ++kc) {
        bf16x8 kf = *(const bf16x8*)(sKb + (n * 16 + l15) * 256 +
                                     (((kc << 2) | quad) ^ l15) * 16);
        sacc[n] = MFMA16(kf, qf[kc], sacc[n]);
      }

    // online softmax: all 16 values belong to this lane's qrow
    float p[4][4];
    float mx = -1e30f;
    if (kb == qb) {  // diagonal tile: causal mask (wave-uniform branch)
      const int key0 = kb * 64 + quad * 4;
#pragma unroll
      for (int n = 0; n < 4; ++n)
#pragma unroll
        for (int r = 0; r < 4; ++r) {
          float s = sacc[n][r];
          s = (key0 + n * 16 + r > qrow) ? -1e30f : s;
          p[n][r] = s;
          mx = fmaxf(mx, s);
        }
    } else {
#pragma unroll
      for (int n = 0; n < 4; ++n)
#pragma unroll
        for (int r = 0; r < 4; ++r) {
          p[n][r] = sacc[n][r];
          mx = fmaxf(mx, sacc[n][r]);
        }
    }
    mx = fmaxf(mx, __shfl_xor(mx, 16, 64));
    mx = fmaxf(mx, __shfl_xor(mx, 32, 64));
    float mnew = fmaxf(m_i, mx);
    float alpha = fexp2(m_i - mnew);
    m_i = mnew;
    float sum = 0.f;
#pragma unroll
    for (int n = 0; n < 4; ++n)
#pragma unroll
      for (int r = 0; r < 4; ++r) {
        p[n][r] = fexp2(p[n][r] - mnew);
        sum += p[n][r];
      }
    sum += __shfl_xor(sum, 16, 64);
    sum += __shfl_xor(sum, 32, 64);
    l_i = l_i * alpha + sum;
#pragma unroll
    for (int nf = 0; nf < 8; ++nf)
#pragma unroll
      for (int r = 0; r < 4; ++r) of[nf][r] *= alpha;

    // pack P to bf16 pairs: pk[n*2+h2] = (p[n][2h2], p[n][2h2+1])
    unsigned pk[8];
#pragma unroll
    for (int n = 0; n < 4; ++n)
#pragma unroll
      for (int h2 = 0; h2 < 2; ++h2) {
        hbf16 t2[2] = {__float2bfloat16(p[n][2 * h2]), __float2bfloat16(p[n][2 * h2 + 1])};
        pk[n * 2 + h2] = *(unsigned*)t2;
      }

    // PV: O^T += V^T · P^T ; P^T B-fragment gathered via shuffles
    const int sa = ((quad & 1) << 5) + l15;  // src lane a: quad'=(quad&1)*2
    const int sb2 = sa + 16;                 // src lane b: quad'=(quad&1)*2+1
#pragma unroll
    for (int kc = 0; kc < 2; ++kc) {
      unsigned a0 = __shfl((int)pk[kc * 4 + 0], sa, 64);
      unsigned a1 = __shfl((int)pk[kc * 4 + 1], sa, 64);
      unsigned a2 = __shfl((int)pk[kc * 4 + 2], sa, 64);
      unsigned a3 = __shfl((int)pk[kc * 4 + 3], sa, 64);
      unsigned b0 = __shfl((int)pk[kc * 4 + 0], sb2, 64);
      unsigned b1 = __shfl((int)pk[kc * 4 + 1], sb2, 64);
      unsigned b2 = __shfl((int)pk[kc * 4 + 2], sb2, 64);
      unsigned b3 = __shfl((int)pk[kc * 4 + 3], sb2, 64);
      union {
        unsigned u[4];
        bf16x8 v;
      } pf;
      pf.u[0] = (quad < 2) ? a0 : a2;
      pf.u[1] = (quad < 2) ? a1 : a3;
      pf.u[2] = (quad < 2) ? b0 : b2;
      pf.u[3] = (quad < 2) ? b1 : b3;
#pragma unroll
      for (int nf = 0; nf < 8; ++nf) {
        bf16x8 vf = *(const bf16x8*)(sVb + (nf * 16 + l15) * 128 +
                                     (((kc << 2) | quad) ^ (l15 & 7)) * 16);
        of[nf] = MFMA16(vf, pf.v, of[nf]);
      }
    }
    __syncthreads();
  }

  const float invl = 1.f / l_i;
#pragma unroll
  for (int nf = 0; nf < 8; ++nf) {
    hbf16 t4[4];
#pragma unroll
    for (int r = 0; r < 4; ++r) t4[r] = __float2bfloat16(of[nf][r] * invl);
    *(uint2*)(O + (size_t)qrow * 4096 + h * 128 + nf * 16 + quad * 4) = *(uint2*)t4;
  }
}

// ---------------------------------------------------------------------- launch
extern "C" void kernel_launch(void* const* d_in, const int* in_sizes, int n_in,
                              void* d_out, int out_size, void* d_ws, size_t ws_size,
                              hipStream_t stream) {
  const float* x = (const float*)d_in[0];
  const float* wq = (const float*)d_in[1];
  const float* wk = (const float*)d_in[2];
  const float* wv = (const float*)d_in[3];
  const float* wo = (const float*)d_in[4];
  const float* fc = (const float*)d_in[5];
  const float* fs = (const float*)d_in[6];
  float* out = (float*)d_out;

  char* w = (char*)d_ws;
  size_t off = 0;
  auto alloc = [&](size_t bytes) -> char* {
    char* p = w + off;
    off += (bytes + 255) & ~(size_t)255;
    return p;
  };
  unsigned int* gmaxs = (unsigned int*)alloc(256 * 8 * 4);
  hbf16* xb = (hbf16*)alloc((size_t)2048 * 4096 * 2);
  hbf16* wqkv = (hbf16*)alloc((size_t)6144 * 4096 * 2);  // stacked wq_q/wk_q/wv_q; later wo_q
  float* qkv = (float*)alloc((size_t)2048 * 6144 * 4);   // fused proj out; later attn_out (bf16)
  hbf16* qrope = (hbf16*)alloc((size_t)2048 * 4096 * 2);
  hbf16* krope = (hbf16*)alloc((size_t)2048 * 1024 * 2);
  hbf16* vt = (hbf16*)alloc((size_t)8 * 128 * 2048 * 2);
  hbf16* woq = wqkv;           // reused after QKV GEMM consumes wqkv
  hbf16* attno = (hbf16*)qkv;  // reused after rope/transpose consume qkv

  const float kSc = 0.12753139668280277f;  // (1/sqrt(128)) * log2(e)

  quant_max_kernel<<<dim3(512, 4), 256, 0, stream>>>(wq, wk, wv, wo, gmaxs);
  prep_kernel<<<dim3(2048, 4), 256, 0, stream>>>(wq, wk, wv, x, wqkv, xb, gmaxs);
  gemm8_kernel<<<dim3(16, 24), 512, 0, stream>>>(xb, wqkv, qkv, 6144);
  postproc_kernel<<<23040, 256, 0, stream>>>(wo, woq, gmaxs, qkv, fc, fs, qrope, krope, vt, kSc);
  attn_kernel<<<1024, 256, 0, stream>>>(qrope, krope, vt, attno);
  gemm8_kernel<<<dim3(16, 16), 512, 0, stream>>>(attno, woq, out, 4096);
  (void)in_sizes; (void)n_in; (void)out_size; (void)ws_size;
}

// Round 2
// 549.013 us; speedup vs baseline: 1.0446x; 1.0121x over previous
//
#include <hip/hip_runtime.h>
#include <hip/hip_bf16.h>

typedef __hip_bfloat16 hbf16;
typedef __bf16 bf16x8 __attribute__((ext_vector_type(8)));
typedef float f32x4 __attribute__((ext_vector_type(4)));

#define MFMA16(a, b, c) __builtin_amdgcn_mfma_f32_16x16x32_bf16((a), (b), (c), 0, 0, 0)

// async global->LDS, 16B per lane. LDS dest = wave-uniform base + lane*16.
#define ASYNC16(ldsaddr, gaddr)                                                        \
  __builtin_amdgcn_global_load_lds(                                                    \
      (__attribute__((address_space(1))) void*)(void*)(gaddr),                         \
      (__attribute__((address_space(3))) void*)(ldsaddr), 16, 0, 0)

static __device__ __forceinline__ float fexp2(float x) {
#if __has_builtin(__builtin_amdgcn_exp2f)
  return __builtin_amdgcn_exp2f(x);
#else
  return exp2f(x);
#endif
}

// ---------------------------------------------------------------- quantization
// grid (512, 4): x = group(64) x split(8); y = matrix {wq,wk,wv,wo}.
__global__ void quant_max_kernel(const float* __restrict__ wq, const float* __restrict__ wk,
                                 const float* __restrict__ wv, const float* __restrict__ wo,
                                 unsigned int* __restrict__ gmaxs) {
  const int my = blockIdx.y;
  const float* W;
  int slotBase, rowsPerSplit;
  if (my == 0) { W = wq; slotBase = 0;   rowsPerSplit = 512; }
  else if (my == 1) { W = wk; slotBase = 64;  rowsPerSplit = 128; }
  else if (my == 2) { W = wv; slotBase = 128; rowsPerSplit = 128; }
  else { W = wo; slotBase = 192; rowsPerSplit = 512; }
  const int tid = threadIdx.x;
  const int group = blockIdx.x & 63;
  const int split = blockIdx.x >> 6;
  const int c4 = (tid & 15) * 4;
  const int rs = tid >> 4;  // 0..15
  const float* base = W + (size_t)(split * rowsPerSplit) * 4096 + group * 64 + c4;
  float m = 0.f;
  for (int r = rs; r < rowsPerSplit; r += 16) {
    float4 v = *(const float4*)(base + (size_t)r * 4096);
    m = fmaxf(m, fmaxf(fmaxf(fabsf(v.x), fabsf(v.y)), fmaxf(fabsf(v.z), fabsf(v.w))));
  }
  for (int d = 1; d < 64; d <<= 1) m = fmaxf(m, __shfl_xor(m, d, 64));
  __shared__ float wm_[4];
  if ((tid & 63) == 0) wm_[tid >> 6] = m;
  __syncthreads();
  if (tid == 0) {
    m = fmaxf(fmaxf(wm_[0], wm_[1]), fmaxf(wm_[2], wm_[3]));
    gmaxs[(slotBase + group) * 8 + split] = __float_as_uint(m);
  }
}

// w_q = trunc(w * 2^(7-gex)) * 2^(gex-7), exact in bf16.
__device__ __forceinline__ void quant_body(const float* __restrict__ W, hbf16* __restrict__ Wq,
                                           const unsigned int* __restrict__ gmaxs, int slotBase,
                                           int n4, int block0, int nblocks) {
  const int stride = nblocks * 256;
  const int idx0 = block0 * 256 + (int)threadIdx.x;
  if (idx0 >= n4) return;
  const int slot = slotBase + ((idx0 & 1023) >> 4);
  unsigned int mb = 0;
#pragma unroll
  for (int sp = 0; sp < 8; ++sp) mb = max(mb, gmaxs[slot * 8 + sp]);
  int gex = (int)((mb >> 23) & 255) - 127;
  float s = __uint_as_float((unsigned)(134 - gex) << 23);    // 2^(7-gex)
  float inv = __uint_as_float((unsigned)(120 + gex) << 23);  // 2^(gex-7)
  for (int idx = idx0; idx < n4; idx += stride) {
    float4 w = *(const float4*)(W + (size_t)idx * 4);
    hbf16 t[4];
    t[0] = __float2bfloat16(truncf(w.x * s) * inv);
    t[1] = __float2bfloat16(truncf(w.y * s) * inv);
    t[2] = __float2bfloat16(truncf(w.z * s) * inv);
    t[3] = __float2bfloat16(truncf(w.w * s) * inv);
    *(uint2*)(Wq + (size_t)idx * 4) = *(uint2*)t;
  }
}

// grid (2048, 4): y=0 wq, y=1 wk, y=2 wv (into stacked wqkv), y=3 x->bf16
__global__ void prep_kernel(const float* __restrict__ wq, const float* __restrict__ wk,
                            const float* __restrict__ wv, const float* __restrict__ x,
                            hbf16* __restrict__ Wqkv, hbf16* __restrict__ xb,
                            const unsigned int* __restrict__ gmaxs) {
  const int my = blockIdx.y;
  if (my == 0) {
    quant_body(wq, Wqkv, gmaxs, 0, 4096 * 4096 / 4, blockIdx.x, gridDim.x);
  } else if (my == 1) {
    quant_body(wk, Wqkv + (size_t)4096 * 4096, gmaxs, 64, 1024 * 4096 / 4, blockIdx.x, gridDim.x);
  } else if (my == 2) {
    quant_body(wv, Wqkv + (size_t)5120 * 4096, gmaxs, 128, 1024 * 4096 / 4, blockIdx.x, gridDim.x);
  } else {
    const int stride = gridDim.x * 256;
    for (int idx = blockIdx.x * 256 + threadIdx.x; idx < 2048 * 4096 / 4; idx += stride) {
      float4 v = *(const float4*)(x + (size_t)idx * 4);
      hbf16 t[4] = {__float2bfloat16(v.x), __float2bfloat16(v.y),
                    __float2bfloat16(v.z), __float2bfloat16(v.w)};
      *(uint2*)(xb + (size_t)idx * 4) = *(uint2*)t;
    }
  }
}

// --------------------------------------------- post-QKV fused dispatch
__global__ void postproc_kernel(const float* __restrict__ wo, hbf16* __restrict__ woq,
                                const unsigned int* __restrict__ gmaxs,
                                const float* __restrict__ qkv, const float* __restrict__ Cs,
                                const float* __restrict__ Sn, hbf16* __restrict__ qrope,
                                hbf16* __restrict__ krope, hbf16* __restrict__ Vt, float qscale) {
  __shared__ float tile[64][65];
  const int bid = blockIdx.x;
  const int tid = threadIdx.x;
  if (bid < 2048) {
    quant_body(wo, woq, gmaxs, 192, 4096 * 4096 / 4, bid, 2048);
  } else if (bid < 18432) {
    int i = (bid - 2048) * 256 + tid;
    int s = i >> 11, p = i & 2047, t = p & 63;
    float2 q = *(const float2*)(qkv + (size_t)s * 6144 + p * 2);
    float c = Cs[s * 64 + t] * qscale, sn = Sn[s * 64 + t] * qscale;
    hbf16 o[2] = {__float2bfloat16(q.x * c - q.y * sn), __float2bfloat16(q.x * sn + q.y * c)};
    *(unsigned int*)(qrope + (size_t)s * 4096 + p * 2) = *(unsigned int*)o;
  } else if (bid < 22528) {
    int i = (bid - 18432) * 256 + tid;
    int s = i >> 9, p = i & 511, t = p & 63;
    float2 q = *(const float2*)(qkv + (size_t)s * 6144 + 4096 + p * 2);
    float c = Cs[s * 64 + t], sn = Sn[s * 64 + t];
    hbf16 o[2] = {__float2bfloat16(q.x * c - q.y * sn), __float2bfloat16(q.x * sn + q.y * c)};
    *(unsigned int*)(krope + (size_t)s * 1024 + p * 2) = *(unsigned int*)o;
  } else {
    int id = bid - 22528;
    int g = id & 7, sb = (id >> 3) & 31, db = id >> 8;
    int c = tid & 63;
    for (int r = tid >> 6; r < 64; r += 4)
      tile[r][c] = qkv[(size_t)(sb * 64 + r) * 6144 + 5120 + g * 128 + db * 64 + c];
    __syncthreads();
    for (int r = tid >> 6; r < 64; r += 4)
      Vt[(size_t)g * 262144 + (size_t)(db * 64 + r) * 2048 + sb * 64 + c] =
          __float2bfloat16(tile[c][r]);
  }
}

// ------------------------------------------------------------------ GEMM C=A*Bt^T
// 256x256 tile, BK=64, 8 waves (2M x 4N). Fragment interleave: wave wm owns
// m-frag j at rows wm*16 + j*32 (A-half = j>>2); wave wn owns n-frag n at cols
// wn*16 + n*64 (B-half = n>>1). So phase (mh,nh) reads exactly A-half mh +
// B-half nh BLOCK-WIDE -> half-tiles rotate at phase granularity:
//   phase 4t+0 (0,0): stage A1(t+1)   [slot free since 4t-2]
//   phase 4t+1 (0,1): stage B1(t+1)   [free since 4t-1]
//   phase 4t+2 (1,0): stage A0(t+2)   [A0(t) freed at 4t+0]
//   phase 4t+3 (1,1): stage B0(t+2)   [B0(t) freed at 4t+2]
// Tile-t halves staged at phases 4t-6..4t-3; single counted wait vmcnt(4) per
// tile (keeps 2 half-tiles = 4 loads in flight, never drains to 0). 16 MFMA per
// barrier pair, setprio(1) around each MFMA cluster. LDS 128 KiB, conflict-free
// chunk^(row&7) swizzle (measured 0 conflicts). KLEN templated for split-K.
template <int KLEN>
__global__ __launch_bounds__(512, 2) void gemm4p_kernel(const hbf16* __restrict__ A,
                                                        const hbf16* __restrict__ Bt,
                                                        float* __restrict__ C0,
                                                        float* __restrict__ C1, int N) {
  constexpr int LDA = 4096;  // element row stride of A and Bt
  constexpr int NT = KLEN / 64;
  __shared__ __align__(16) char smem[131072];
  const int tid = threadIdx.x;
  const int wave = tid >> 6, lane = tid & 63;
  const int l15 = lane & 15, quad = lane >> 4;
  const int wm = wave >> 2, wn = wave & 3;
  const int bm = blockIdx.x, bn = blockIdx.y, bz = blockIdx.z;
  float* C = bz ? C1 : C0;

  const char* Ab = (const char*)(A + (size_t)bm * 256 * LDA + bz * KLEN);
  const char* Bb = (const char*)(Bt + (size_t)bn * 256 * LDA + bz * KLEN);
  char* sm = (char*)smem;

  // slot byte offsets: A(par,mh), B(par,nh) -- 16 KB each (128 rows x 128 B)
#define SA_(par, mh) (((par)*2 + (mh)) * 16384)
#define SB_(par, nh) (65536 + ((par)*2 + (nh)) * 16384)

  f32x4 acc[8][4];
#pragma unroll
  for (int i = 0; i < 8; ++i)
#pragma unroll
    for (int n = 0; n < 4; ++n) acc[i][n] = (f32x4){0.f, 0.f, 0.f, 0.f};

  // stage one 16 KB half-tile (2 x 8KB async calls); tu clamped at tail
  auto stage = [&](int slotOff, const char* gb, int rowOff, int tu) {
    const int kk = ((tu < NT) ? tu : NT - 1) * 64;
#pragma unroll
    for (int r = 0; r < 2; ++r) {
      int f = r * 8192 + tid * 16;
      int row = f >> 7;
      int lc = ((f >> 4) & 7) ^ (row & 7);
      ASYNC16(sm + slotOff + f, gb + (size_t)(rowOff + row) * (LDA * 2) + kk * 2 + lc * 16);
    }
  };

  // prologue: tile0 all 4 halves, tile1 first 2; wait until tile0 landed.
  stage(SA_(0, 0), Ab, 0, 0);
  stage(SB_(0, 0), Bb, 0, 0);
  stage(SA_(0, 1), Ab, 128, 0);
  stage(SB_(0, 1), Bb, 128, 0);
  stage(SA_(1, 0), Ab, 0, 1);
  stage(SB_(1, 0), Bb, 0, 1);
  asm volatile("s_waitcnt vmcnt(4)" ::: "memory");
  __builtin_amdgcn_s_barrier();

  const int aoff = (wm * 16 + l15) * 128;
  const int boff = (wn * 16 + l15) * 128;
  const int cx0 = (quad ^ (l15 & 7)) * 16;        // kc=0 chunk (row&7 == l15&7)
  const int cx1 = ((4 | quad) ^ (l15 & 7)) * 16;  // kc=1 chunk

  for (int t = 0; t < NT; ++t) {
    const int par = t & 1, par1 = par ^ 1;
    bf16x8 af[2][4], bg[2][2];

    // ---- phase (0,0): A-half0 frags + B-half0 frags; stage A1(t+1)
#pragma unroll
    for (int mf = 0; mf < 4; ++mf) {
      af[0][mf] = *(const bf16x8*)(sm + SA_(par, 0) + aoff + mf * 4096 + cx0);
      af[1][mf] = *(const bf16x8*)(sm + SA_(par, 0) + aoff + mf * 4096 + cx1);
    }
#pragma unroll
    for (int nf = 0; nf < 2; ++nf) {
      bg[0][nf] = *(const bf16x8*)(sm + SB_(par, 0) + boff + nf * 8192 + cx0);
      bg[1][nf] = *(const bf16x8*)(sm + SB_(par, 0) + boff + nf * 8192 + cx1);
    }
    stage(SA_(par1, 1), Ab, 128, t + 1);
    __builtin_amdgcn_s_barrier();
    __builtin_amdgcn_s_setprio(1);
#pragma unroll
    for (int kc = 0; kc < 2; ++kc)
#pragma unroll
      for (int mf = 0; mf < 4; ++mf)
#pragma unroll
        for (int nf = 0; nf < 2; ++nf) acc[mf][nf] = MFMA16(af[kc][mf], bg[kc][nf], acc[mf][nf]);
    __builtin_amdgcn_s_setprio(0);
    __builtin_amdgcn_s_barrier();

    // ---- phase (0,1): B-half1 frags (A reused); stage B1(t+1)
#pragma unroll
    for (int nf = 0; nf < 2; ++nf) {
      bg[0][nf] = *(const bf16x8*)(sm + SB_(par, 1) + boff + nf * 8192 + cx0);
      bg[1][nf] = *(const bf16x8*)(sm + SB_(par, 1) + boff + nf * 8192 + cx1);
    }
    stage(SB_(par1, 1), Bb, 128, t + 1);
    __builtin_amdgcn_s_barrier();
    __builtin_amdgcn_s_setprio(1);
#pragma unroll
    for (int kc = 0; kc < 2; ++kc)
#pragma unroll
      for (int mf = 0; mf < 4; ++mf)
#pragma unroll
        for (int nf = 0; nf < 2; ++nf)
          acc[mf][nf + 2] = MFMA16(af[kc][mf], bg[kc][nf], acc[mf][nf + 2]);
    __builtin_amdgcn_s_setprio(0);
    __builtin_amdgcn_s_barrier();

    // ---- phase (1,0): A-half1 + B-half0 frags; stage A0(t+2)
#pragma unroll
    for (int mf = 0; mf < 4; ++mf) {
      af[0][mf] = *(const bf16x8*)(sm + SA_(par, 1) + aoff + mf * 4096 + cx0);
      af[1][mf] = *(const bf16x8*)(sm + SA_(par, 1) + aoff + mf * 4096 + cx1);
    }
#pragma unroll
    for (int nf = 0; nf < 2; ++nf) {
      bg[0][nf] = *(const bf16x8*)(sm + SB_(par, 0) + boff + nf * 8192 + cx0);
      bg[1][nf] = *(const bf16x8*)(sm + SB_(par, 0) + boff + nf * 8192 + cx1);
    }
    stage(SA_(par, 0), Ab, 0, t + 2);
    __builtin_amdgcn_s_barrier();
    __builtin_amdgcn_s_setprio(1);
#pragma unroll
    for (int kc = 0; kc < 2; ++kc)
#pragma unroll
      for (int mf = 0; mf < 4; ++mf)
#pragma unroll
        for (int nf = 0; nf < 2; ++nf)
          acc[mf + 4][nf] = MFMA16(af[kc][mf], bg[kc][nf], acc[mf + 4][nf]);
    __builtin_amdgcn_s_setprio(0);
    __builtin_amdgcn_s_barrier();

    // ---- phase (1,1): B-half1 frags (A reused); stage B0(t+2); counted wait
#pragma unroll
    for (int nf = 0; nf < 2; ++nf) {
      bg[0][nf] = *(const bf16x8*)(sm + SB_(par, 1) + boff + nf * 8192 + cx0);
      bg[1][nf] = *(const bf16x8*)(sm + SB_(par, 1) + boff + nf * 8192 + cx1);
    }
    stage(SB_(par, 0), Bb, 0, t + 2);
    __builtin_amdgcn_s_barrier();
    __builtin_amdgcn_s_setprio(1);
#pragma unroll
    for (int kc = 0; kc < 2; ++kc)
#pragma unroll
      for (int mf = 0; mf < 4; ++mf)
#pragma unroll
        for (int nf = 0; nf < 2; ++nf)
          acc[mf + 4][nf + 2] = MFMA16(af[kc][mf], bg[kc][nf], acc[mf + 4][nf + 2]);
    __builtin_amdgcn_s_setprio(0);
    asm volatile("s_waitcnt vmcnt(4)" ::: "memory");
    __builtin_amdgcn_s_barrier();
  }
  asm volatile("s_waitcnt vmcnt(0)" ::: "memory");  // drain tail dummy stages

#pragma unroll
  for (int j = 0; j < 8; ++j) {
    const int row = bm * 256 + wm * 16 + j * 32 + quad * 4;
#pragma unroll
    for (int n = 0; n < 4; ++n) {
      float* cp = C + (size_t)row * N + bn * 256 + wn * 16 + n * 64 + l15;
#pragma unroll
      for (int r = 0; r < 4; ++r) cp[(size_t)r * N] = acc[j][n][r];
    }
  }
#undef SA_
#undef SB_
}

// split-K reduction: out += c1 (exact grid, no loop)
__global__ void addf4_kernel(float* __restrict__ o, const float* __restrict__ a) {
  const int i = blockIdx.x * 256 + threadIdx.x;
  float4 x = ((const float4*)o)[i];
  float4 y = ((const float4*)a)[i];
  x.x += y.x; x.y += y.y; x.z += y.z; x.w += y.w;
  ((float4*)o)[i] = x;
}

// ------------------------------------------------------------- flash attention
__global__ __launch_bounds__(256, 4) void attn_kernel(const hbf16* __restrict__ Q,
                                                      const hbf16* __restrict__ Kr,
                                                      const hbf16* __restrict__ Vt,
                                                      hbf16* __restrict__ O) {
  __shared__ __align__(16) hbf16 sK[64 * 128];  // [key][d], chunk^(key&15) swizzle
  __shared__ __align__(16) hbf16 sV[128 * 64];  // [d][key], chunk^(d&7) swizzle
  const int tid = threadIdx.x;
  const int wave = tid >> 6, lane = tid & 63;
  const int l15 = lane & 15, quad = lane >> 4;
  const int bid = blockIdx.x;
  const int h = bid >> 5;
  const int qb = (31 - (bid & 31) + 8 * ((bid >> 8) & 3)) & 31;
  const int g = h >> 2;
  const int qrow0 = qb * 64 + wave * 16;
  const int qrow = qrow0 + l15;

  bf16x8 qf[4];
  {
    const hbf16* qp = Q + (size_t)qrow * 4096 + h * 128 + quad * 8;
#pragma unroll
    for (int kc = 0; kc < 4; ++kc) qf[kc] = *(const bf16x8*)(qp + kc * 32);
  }
  f32x4 of[8];
#pragma unroll
  for (int nf = 0; nf < 8; ++nf) of[nf] = (f32x4){0.f, 0.f, 0.f, 0.f};
  float m_i = -1e30f, l_i = 0.f;

  const char* Kb = (const char*)Kr + (size_t)g * 256;
  const char* Vb = (const char*)Vt + (size_t)g * 524288;
  char* sKb = (char*)sK;
  char* sVb = (char*)sV;

  const int nkb = qb + 1;
  for (int kb = 0; kb < nkb; ++kb) {
#pragma unroll
    for (int r = 0; r < 4; ++r) {
      int f = r * 4096 + tid * 16;
      {
        int row = f >> 8;
        int lc = ((f >> 4) & 15) ^ (row & 15);
        ASYNC16(sKb + f, Kb + (size_t)(kb * 64 + row) * 2048 + lc * 16);
      }
      {
        int row = f >> 7;
        int lc = ((f >> 4) & 7) ^ (row & 7);
        ASYNC16(sVb + f, Vb + (size_t)row * 4096 + kb * 128 + lc * 16);
      }
    }
    __syncthreads();

    f32x4 sacc[4];
#pragma unroll
    for (int n = 0; n < 4; ++n) sacc[n] = (f32x4){0.f, 0.f, 0.f, 0.f};
#pragma unroll
    for (int n = 0; n < 4; ++n)
#pragma unroll
      for (int kc = 0; kc < 4; ++kc) {
        bf16x8 kf = *(const bf16x8*)(sKb + (n * 16 + l15) * 256 +
                                     (((kc << 2) | quad) ^ l15) * 16);
        sacc[n] = MFMA16(kf, qf[kc], sacc[n]);
      }

    float p[4][4];
    float mx = -1e30f;
    if (kb == qb) {
      const int key0 = kb * 64 + quad * 4;
#pragma unroll
      for (int n = 0; n < 4; ++n)
#pragma unroll
        for (int r = 0; r < 4; ++r) {
          float s = sacc[n][r];
          s = (key0 + n * 16 + r > qrow) ? -1e30f : s;
          p[n][r] = s;
          mx = fmaxf(mx, s);
        }
    } else {
#pragma unroll
      for (int n = 0; n < 4; ++n)
#pragma unroll
        for (int r = 0; r < 4; ++r) {
          p[n][r] = sacc[n][r];
          mx = fmaxf(mx, sacc[n][r]);
        }
    }
    mx = fmaxf(mx, __shfl_xor(mx, 16, 64));
    mx = fmaxf(mx, __shfl_xor(mx, 32, 64));
    float mnew = fmaxf(m_i, mx);
    float alpha = fexp2(m_i - mnew);
    m_i = mnew;
    float sum = 0.f;
#pragma unroll
    for (int n = 0; n < 4; ++n)
#pragma unroll
      for (int r = 0; r < 4; ++r) {
        p[n][r] = fexp2(p[n][r] - mnew);
        sum += p[n][r];
      }
    sum += __shfl_xor(sum, 16, 64);
    sum += __shfl_xor(sum, 32, 64);
    l_i = l_i * alpha + sum;
#pragma unroll
    for (int nf = 0; nf < 8; ++nf)
#pragma unroll
      for (int r = 0; r < 4; ++r) of[nf][r] *= alpha;

    unsigned pk[8];
#pragma unroll
    for (int n = 0; n < 4; ++n)
#pragma unroll
      for (int h2 = 0; h2 < 2; ++h2) {
        hbf16 t2[2] = {__float2bfloat16(p[n][2 * h2]), __float2bfloat16(p[n][2 * h2 + 1])};
        pk[n * 2 + h2] = *(unsigned*)t2;
      }

    const int sa = ((quad & 1) << 5) + l15;
    const int sb2 = sa + 16;
#pragma unroll
    for (int kc = 0; kc < 2; ++kc) {
      unsigned a0 = __shfl((int)pk[kc * 4 + 0], sa, 64);
      unsigned a1 = __shfl((int)pk[kc * 4 + 1], sa, 64);
      unsigned a2 = __shfl((int)pk[kc * 4 + 2], sa, 64);
      unsigned a3 = __shfl((int)pk[kc * 4 + 3], sa, 64);
      unsigned b0 = __shfl((int)pk[kc * 4 + 0], sb2, 64);
      unsigned b1 = __shfl((int)pk[kc * 4 + 1], sb2, 64);
      unsigned b2 = __shfl((int)pk[kc * 4 + 2], sb2, 64);
      unsigned b3 = __shfl((int)pk[kc * 4 + 3], sb2, 64);
      union {
        unsigned u[4];
        bf16x8 v;
      } pf;
      pf.u[0] = (quad < 2) ? a0 : a2;
      pf.u[1] = (quad < 2) ? a1 : a3;
      pf.u[2] = (quad < 2) ? b0 : b2;
      pf.u[3] = (quad < 2) ? b1 : b3;
#pragma unroll
      for (int nf = 0; nf < 8; ++nf) {
        bf16x8 vf = *(const bf16x8*)(sVb + (nf * 16 + l15) * 128 +
                                     (((kc << 2) | quad) ^ (l15 & 7)) * 16);
        of[nf] = MFMA16(vf, pf.v, of[nf]);
      }
    }
    __syncthreads();
  }

  const float invl = 1.f / l_i;
#pragma unroll
  for (int nf = 0; nf < 8; ++nf) {
    hbf16 t4[4];
#pragma unroll
    for (int r = 0; r < 4; ++r) t4[r] = __float2bfloat16(of[nf][r] * invl);
    *(uint2*)(O + (size_t)qrow * 4096 + h * 128 + nf * 16 + quad * 4) = *(uint2*)t4;
  }
}

// ---------------------------------------------------------------------- launch
extern "C" void kernel_launch(void* const* d_in, const int* in_sizes, int n_in,
                              void* d_out, int out_size, void* d_ws, size_t ws_size,
                              hipStream_t stream) {
  const float* x = (const float*)d_in[0];
  const float* wq = (const float*)d_in[1];
  const float* wk = (const float*)d_in[2];
  const float* wv = (const float*)d_in[3];
  const float* wo = (const float*)d_in[4];
  const float* fc = (const float*)d_in[5];
  const float* fs = (const float*)d_in[6];
  float* out = (float*)d_out;

  char* w = (char*)d_ws;
  size_t off = 0;
  auto alloc = [&](size_t bytes) -> char* {
    char* p = w + off;
    off += (bytes + 255) & ~(size_t)255;
    return p;
  };
  unsigned int* gmaxs = (unsigned int*)alloc(256 * 8 * 4);
  hbf16* xb = (hbf16*)alloc((size_t)2048 * 4096 * 2);
  hbf16* wqkv = (hbf16*)alloc((size_t)6144 * 4096 * 2);  // stacked wq_q/wk_q/wv_q; later wo_q
  float* qkv = (float*)alloc((size_t)2048 * 6144 * 4);   // fused proj out; later attno + c1
  hbf16* qrope = (hbf16*)alloc((size_t)2048 * 4096 * 2);
  hbf16* krope = (hbf16*)alloc((size_t)2048 * 1024 * 2);
  hbf16* vt = (hbf16*)alloc((size_t)8 * 128 * 2048 * 2);
  hbf16* woq = wqkv;           // reused after QKV GEMM consumes wqkv
  hbf16* attno = (hbf16*)qkv;  // first 16.8 MB of qkv buffer (consumed by then)
  float* c1 = (float*)((char*)qkv + (size_t)2048 * 4096 * 2);  // split-K partial (33.5 MB)

  const float kSc = 0.12753139668280277f;  // (1/sqrt(128)) * log2(e)

  quant_max_kernel<<<dim3(512, 4), 256, 0, stream>>>(wq, wk, wv, wo, gmaxs);
  prep_kernel<<<dim3(2048, 4), 256, 0, stream>>>(wq, wk, wv, x, wqkv, xb, gmaxs);
  gemm4p_kernel<4096><<<dim3(8, 24), 512, 0, stream>>>(xb, wqkv, qkv, qkv, 6144);
  postproc_kernel<<<23040, 256, 0, stream>>>(wo, woq, gmaxs, qkv, fc, fs, qrope, krope, vt, kSc);
  attn_kernel<<<1024, 256, 0, stream>>>(qrope, krope, vt, attno);
  gemm4p_kernel<2048><<<dim3(8, 16, 2), 512, 0, stream>>>(attno, woq, out, c1, 4096);
  addf4_kernel<<<8192, 256, 0, stream>>>(out, c1);
  (void)in_sizes; (void)n_in; (void)out_size; (void)ws_size;
}

// Round 3
// 511.575 us; speedup vs baseline: 1.1211x; 1.0732x over previous
//
#include <hip/hip_runtime.h>
#include <hip/hip_bf16.h>

typedef __hip_bfloat16 hbf16;
typedef __bf16 bf16x8 __attribute__((ext_vector_type(8)));
typedef float f32x4 __attribute__((ext_vector_type(4)));

#define MFMA16(a, b, c) __builtin_amdgcn_mfma_f32_16x16x32_bf16((a), (b), (c), 0, 0, 0)

// async global->LDS, 16B per lane. LDS dest = wave-uniform base + lane*16.
#define ASYNC16(ldsaddr, gaddr)                                                        \
  __builtin_amdgcn_global_load_lds(                                                    \
      (__attribute__((address_space(1))) void*)(void*)(gaddr),                         \
      (__attribute__((address_space(3))) void*)(ldsaddr), 16, 0, 0)

static __device__ __forceinline__ float fexp2(float x) {
#if __has_builtin(__builtin_amdgcn_exp2f)
  return __builtin_amdgcn_exp2f(x);
#else
  return exp2f(x);
#endif
}

// ---------------------------------------------------------------- quantization
// grid (512, 4): x = group(64) x split(8); y = matrix {wq,wk,wv,wo}.
__global__ void quant_max_kernel(const float* __restrict__ wq, const float* __restrict__ wk,
                                 const float* __restrict__ wv, const float* __restrict__ wo,
                                 unsigned int* __restrict__ gmaxs) {
  const int my = blockIdx.y;
  const float* W;
  int slotBase, rowsPerSplit;
  if (my == 0) { W = wq; slotBase = 0;   rowsPerSplit = 512; }
  else if (my == 1) { W = wk; slotBase = 64;  rowsPerSplit = 128; }
  else if (my == 2) { W = wv; slotBase = 128; rowsPerSplit = 128; }
  else { W = wo; slotBase = 192; rowsPerSplit = 512; }
  const int tid = threadIdx.x;
  const int group = blockIdx.x & 63;
  const int split = blockIdx.x >> 6;
  const int c4 = (tid & 15) * 4;
  const int rs = tid >> 4;  // 0..15
  const float* base = W + (size_t)(split * rowsPerSplit) * 4096 + group * 64 + c4;
  float m = 0.f;
  for (int r = rs; r < rowsPerSplit; r += 16) {
    float4 v = *(const float4*)(base + (size_t)r * 4096);
    m = fmaxf(m, fmaxf(fmaxf(fabsf(v.x), fabsf(v.y)), fmaxf(fabsf(v.z), fabsf(v.w))));
  }
  for (int d = 1; d < 64; d <<= 1) m = fmaxf(m, __shfl_xor(m, d, 64));
  __shared__ float wm_[4];
  if ((tid & 63) == 0) wm_[tid >> 6] = m;
  __syncthreads();
  if (tid == 0) {
    m = fmaxf(fmaxf(wm_[0], wm_[1]), fmaxf(wm_[2], wm_[3]));
    gmaxs[(slotBase + group) * 8 + split] = __float_as_uint(m);
  }
}

// w_q = trunc(w * 2^(7-gex)) * 2^(gex-7), exact in bf16.
__device__ __forceinline__ void quant_body(const float* __restrict__ W, hbf16* __restrict__ Wq,
                                           const unsigned int* __restrict__ gmaxs, int slotBase,
                                           int n4, int block0, int nblocks) {
  const int stride = nblocks * 256;
  const int idx0 = block0 * 256 + (int)threadIdx.x;
  if (idx0 >= n4) return;
  const int slot = slotBase + ((idx0 & 1023) >> 4);
  unsigned int mb = 0;
#pragma unroll
  for (int sp = 0; sp < 8; ++sp) mb = max(mb, gmaxs[slot * 8 + sp]);
  int gex = (int)((mb >> 23) & 255) - 127;
  float s = __uint_as_float((unsigned)(134 - gex) << 23);    // 2^(7-gex)
  float inv = __uint_as_float((unsigned)(120 + gex) << 23);  // 2^(gex-7)
  for (int idx = idx0; idx < n4; idx += stride) {
    float4 w = *(const float4*)(W + (size_t)idx * 4);
    hbf16 t[4];
    t[0] = __float2bfloat16(truncf(w.x * s) * inv);
    t[1] = __float2bfloat16(truncf(w.y * s) * inv);
    t[2] = __float2bfloat16(truncf(w.z * s) * inv);
    t[3] = __float2bfloat16(truncf(w.w * s) * inv);
    *(uint2*)(Wq + (size_t)idx * 4) = *(uint2*)t;
  }
}

// grid (2048, 4): y=0 wq, y=1 wk, y=2 wv (into stacked wqkv), y=3 x->bf16
__global__ void prep_kernel(const float* __restrict__ wq, const float* __restrict__ wk,
                            const float* __restrict__ wv, const float* __restrict__ x,
                            hbf16* __restrict__ Wqkv, hbf16* __restrict__ xb,
                            const unsigned int* __restrict__ gmaxs) {
  const int my = blockIdx.y;
  if (my == 0) {
    quant_body(wq, Wqkv, gmaxs, 0, 4096 * 4096 / 4, blockIdx.x, gridDim.x);
  } else if (my == 1) {
    quant_body(wk, Wqkv + (size_t)4096 * 4096, gmaxs, 64, 1024 * 4096 / 4, blockIdx.x, gridDim.x);
  } else if (my == 2) {
    quant_body(wv, Wqkv + (size_t)5120 * 4096, gmaxs, 128, 1024 * 4096 / 4, blockIdx.x, gridDim.x);
  } else {
    const int stride = gridDim.x * 256;
    for (int idx = blockIdx.x * 256 + threadIdx.x; idx < 2048 * 4096 / 4; idx += stride) {
      float4 v = *(const float4*)(x + (size_t)idx * 4);
      hbf16 t[4] = {__float2bfloat16(v.x), __float2bfloat16(v.y),
                    __float2bfloat16(v.z), __float2bfloat16(v.w)};
      *(uint2*)(xb + (size_t)idx * 4) = *(uint2*)t;
    }
  }
}

// --------------------------------------------- post-QKV fused dispatch
__global__ void postproc_kernel(const float* __restrict__ wo, hbf16* __restrict__ woq,
                                const unsigned int* __restrict__ gmaxs,
                                const float* __restrict__ qkv, const float* __restrict__ Cs,
                                const float* __restrict__ Sn, hbf16* __restrict__ qrope,
                                hbf16* __restrict__ krope, hbf16* __restrict__ Vt, float qscale) {
  __shared__ float tile[64][65];
  const int bid = blockIdx.x;
  const int tid = threadIdx.x;
  if (bid < 2048) {
    quant_body(wo, woq, gmaxs, 192, 4096 * 4096 / 4, bid, 2048);
  } else if (bid < 18432) {
    int i = (bid - 2048) * 256 + tid;
    int s = i >> 11, p = i & 2047, t = p & 63;
    float2 q = *(const float2*)(qkv + (size_t)s * 6144 + p * 2);
    float c = Cs[s * 64 + t] * qscale, sn = Sn[s * 64 + t] * qscale;
    hbf16 o[2] = {__float2bfloat16(q.x * c - q.y * sn), __float2bfloat16(q.x * sn + q.y * c)};
    *(unsigned int*)(qrope + (size_t)s * 4096 + p * 2) = *(unsigned int*)o;
  } else if (bid < 22528) {
    int i = (bid - 18432) * 256 + tid;
    int s = i >> 9, p = i & 511, t = p & 63;
    float2 q = *(const float2*)(qkv + (size_t)s * 6144 + 4096 + p * 2);
    float c = Cs[s * 64 + t], sn = Sn[s * 64 + t];
    hbf16 o[2] = {__float2bfloat16(q.x * c - q.y * sn), __float2bfloat16(q.x * sn + q.y * c)};
    *(unsigned int*)(krope + (size_t)s * 1024 + p * 2) = *(unsigned int*)o;
  } else {
    int id = bid - 22528;
    int g = id & 7, sb = (id >> 3) & 31, db = id >> 8;
    int c = tid & 63;
    for (int r = tid >> 6; r < 64; r += 4)
      tile[r][c] = qkv[(size_t)(sb * 64 + r) * 6144 + 5120 + g * 128 + db * 64 + c];
    __syncthreads();
    for (int r = tid >> 6; r < 64; r += 4)
      Vt[(size_t)g * 262144 + (size_t)(db * 64 + r) * 2048 + sb * 64 + c] =
          __float2bfloat16(tile[c][r]);
  }
}

// ------------------------------------------------------------------ GEMM C=A*Bt^T
// 128 x (NFRAG*64) tile, BK=64, 8 waves 2M x 4N. Fragment interleave: wave wm
// owns m-frag j at rows wm*16 + j*32 (A-half = j>>1, 64 rows = ONE 8KB stage
// call); wave wn owns n-frag n at cols wn*16 + n*64 (B-half = n>=NFRAG/2,
// NFRAG*32 rows = NFRAG/2 stage calls). Phase (mh,nh) reads A-half mh + B-half
// nh block-wide; both B-half fragment sets are KEPT IN REGISTERS across the
// tile (bg0/bg1) so phases (1,0)/(1,1) issue no B re-reads (20 ds_read/wave/
// tile instead of 32). Half-slot rotation (2 parities):
//   phase 4t+0 (0,0): stage A1(t+1)  [slot last read at t-1 phase (1,0)]
//   phase 4t+1 (0,1): stage B1(t+1)  [last read at t-1 phase (0,1)]
//   phase 4t+2 (1,0): stage A0(t+2)  [A0(t) last read at 4t+0]
//   phase 4t+3 (1,1): stage B0(t+2)  [B0(t) last read at 4t+0]
// Single counted wait vmcnt(1+NFRAG/2) per tile: at end of tile t the
// outstanding queue is [A0(t+1),B0(t+1),A1(t+1),B1(t+1),A0(t+2),B0(t+2)];
// keeping the newest 1+NFRAG/2 retires everything tile t+1 reads. Never
// drains to 0 in the loop. setprio(1) around each 2*NFRAG-MFMA cluster.
// QKV: NFRAG=6 (tile 128x384, LDS 128KB, grid 16x16=256 = full machine).
// WO:  NFRAG=4 (tile 128x256, LDS  96KB, grid 16x16=256, full K, no split).
template <int NFRAG>
__global__ __launch_bounds__(512, 2) void gemm_tp_kernel(const hbf16* __restrict__ A,
                                                         const hbf16* __restrict__ Bt,
                                                         float* __restrict__ C, int N) {
  constexpr int K = 4096;     // element row stride and K-extent of A and Bt
  constexpr int NT = K / 64;  // 64 K-tiles
  constexpr int HB = NFRAG / 2;       // B-frags per half
  constexpr int SBSZ = NFRAG * 4096;  // B-half slot bytes (NFRAG*32 rows x 128B)
  constexpr int VM = 1 + HB;          // calls left in flight after tile-end wait
  __shared__ __align__(16) char smem[32768 + 4 * SBSZ];
  const int tid = threadIdx.x;
  const int wave = tid >> 6, lane = tid & 63;
  const int l15 = lane & 15, quad = lane >> 4;
  const int wm = wave >> 2, wn = wave & 3;
  const int bm = blockIdx.x, bn = blockIdx.y;

  const char* Ab = (const char*)(A + (size_t)bm * 128 * K);
  const char* Bb = (const char*)(Bt + (size_t)bn * (NFRAG * 64) * K);
  char* sm = (char*)smem;

  // slot byte offsets: A(par,mh) 8KB each; B(par,nh) SBSZ each
#define SA_(par, mh) (((par)*2 + (mh)) * 8192)
#define SB_(par, nh) (32768 + ((par)*2 + (nh)) * SBSZ)

  f32x4 acc[4][NFRAG];
#pragma unroll
  for (int i = 0; i < 4; ++i)
#pragma unroll
    for (int n = 0; n < NFRAG; ++n) acc[i][n] = (f32x4){0.f, 0.f, 0.f, 0.f};

  // A-half: 64 rows x 128B = one 8KB call. tu clamped at tail (dummy restage).
  auto stageA = [&](int slotOff, int rowOff, int tu) {
    const int kk = ((tu < NT) ? tu : NT - 1) * 64;
    int f = tid * 16;
    int row = f >> 7;
    int lc = ((f >> 4) & 7) ^ (row & 7);
    ASYNC16(sm + slotOff + f, Ab + (size_t)(rowOff + row) * (K * 2) + kk * 2 + lc * 16);
  };
  // B-half: NFRAG*32 rows x 128B = NFRAG/2 8KB calls.
  auto stageB = [&](int slotOff, int rowOff, int tu) {
    const int kk = ((tu < NT) ? tu : NT - 1) * 64;
#pragma unroll
    for (int r = 0; r < HB; ++r) {
      int f = r * 8192 + tid * 16;
      int row = f >> 7;
      int lc = ((f >> 4) & 7) ^ (row & 7);
      ASYNC16(sm + slotOff + f, Bb + (size_t)(rowOff + row) * (K * 2) + kk * 2 + lc * 16);
    }
  };

  // prologue: tile0 all 4 halves, tile1 halves (A0,B0); wait until tile0 landed.
  stageA(SA_(0, 0), 0, 0);
  stageB(SB_(0, 0), 0, 0);
  stageA(SA_(0, 1), 64, 0);
  stageB(SB_(0, 1), NFRAG * 32, 0);
  stageA(SA_(1, 0), 0, 1);
  stageB(SB_(1, 0), 0, 1);
  asm volatile("s_waitcnt vmcnt(%0)" ::"i"(VM) : "memory");
  __builtin_amdgcn_s_barrier();

  const int cx0 = (quad ^ (l15 & 7)) * 16;        // kc=0 chunk
  const int cx1 = ((4 | quad) ^ (l15 & 7)) * 16;  // kc=1 chunk

  for (int t = 0; t < NT; ++t) {
    const int par = t & 1, par1 = par ^ 1;
    bf16x8 af[2][2], bg0[2][HB], bg1[2][HB];

    // ---- phase (0,0): A-half0 frags + B-half0 frags; stage A1(t+1)
#pragma unroll
    for (int jl = 0; jl < 2; ++jl) {
      const int ro = (wm * 16 + jl * 32 + l15) * 128;
      af[0][jl] = *(const bf16x8*)(sm + SA_(par, 0) + ro + cx0);
      af[1][jl] = *(const bf16x8*)(sm + SA_(par, 0) + ro + cx1);
    }
#pragma unroll
    for (int nl = 0; nl < HB; ++nl) {
      const int ro = (wn * 16 + nl * 64 + l15) * 128;
      bg0[0][nl] = *(const bf16x8*)(sm + SB_(par, 0) + ro + cx0);
      bg0[1][nl] = *(const bf16x8*)(sm + SB_(par, 0) + ro + cx1);
    }
    stageA(SA_(par1, 1), 64, t + 1);
    __builtin_amdgcn_s_barrier();
    __builtin_amdgcn_s_setprio(1);
#pragma unroll
    for (int kc = 0; kc < 2; ++kc)
#pragma unroll
      for (int jl = 0; jl < 2; ++jl)
#pragma unroll
        for (int nl = 0; nl < HB; ++nl)
          acc[jl][nl] = MFMA16(af[kc][jl], bg0[kc][nl], acc[jl][nl]);
    __builtin_amdgcn_s_setprio(0);
    __builtin_amdgcn_s_barrier();

    // ---- phase (0,1): B-half1 frags (A reused); stage B1(t+1)
#pragma unroll
    for (int nl = 0; nl < HB; ++nl) {
      const int ro = (wn * 16 + nl * 64 + l15) * 128;
      bg1[0][nl] = *(const bf16x8*)(sm + SB_(par, 1) + ro + cx0);
      bg1[1][nl] = *(const bf16x8*)(sm + SB_(par, 1) + ro + cx1);
    }
    stageB(SB_(par1, 1), NFRAG * 32, t + 1);
    __builtin_amdgcn_s_barrier();
    __builtin_amdgcn_s_setprio(1);
#pragma unroll
    for (int kc = 0; kc < 2; ++kc)
#pragma unroll
      for (int jl = 0; jl < 2; ++jl)
#pragma unroll
        for (int nl = 0; nl < HB; ++nl)
          acc[jl][HB + nl] = MFMA16(af[kc][jl], bg1[kc][nl], acc[jl][HB + nl]);
    __builtin_amdgcn_s_setprio(0);
    __builtin_amdgcn_s_barrier();

    // ---- phase (1,0): A-half1 frags (B-half0 from regs); stage A0(t+2)
#pragma unroll
    for (int jl = 0; jl < 2; ++jl) {
      const int ro = (wm * 16 + jl * 32 + l15) * 128;
      af[0][jl] = *(const bf16x8*)(sm + SA_(par, 1) + ro + cx0);
      af[1][jl] = *(const bf16x8*)(sm + SA_(par, 1) + ro + cx1);
    }
    stageA(SA_(par, 0), 0, t + 2);
    __builtin_amdgcn_s_barrier();
    __builtin_amdgcn_s_setprio(1);
#pragma unroll
    for (int kc = 0; kc < 2; ++kc)
#pragma unroll
      for (int jl = 0; jl < 2; ++jl)
#pragma unroll
        for (int nl = 0; nl < HB; ++nl)
          acc[2 + jl][nl] = MFMA16(af[kc][jl], bg0[kc][nl], acc[2 + jl][nl]);
    __builtin_amdgcn_s_setprio(0);
    __builtin_amdgcn_s_barrier();

    // ---- phase (1,1): all from regs; stage B0(t+2); counted wait
    stageB(SB_(par, 0), 0, t + 2);
    __builtin_amdgcn_s_barrier();
    __builtin_amdgcn_s_setprio(1);
#pragma unroll
    for (int kc = 0; kc < 2; ++kc)
#pragma unroll
      for (int jl = 0; jl < 2; ++jl)
#pragma unroll
        for (int nl = 0; nl < HB; ++nl)
          acc[2 + jl][HB + nl] = MFMA16(af[kc][jl], bg1[kc][nl], acc[2 + jl][HB + nl]);
    __builtin_amdgcn_s_setprio(0);
    asm volatile("s_waitcnt vmcnt(%0)" ::"i"(VM) : "memory");
    __builtin_amdgcn_s_barrier();
  }
  asm volatile("s_waitcnt vmcnt(0)" ::: "memory");  // drain tail dummy stages

#pragma unroll
  for (int j = 0; j < 4; ++j) {
    const int row = bm * 128 + wm * 16 + j * 32 + quad * 4;
#pragma unroll
    for (int n = 0; n < NFRAG; ++n) {
      float* cp = C + (size_t)row * N + bn * (NFRAG * 64) + wn * 16 + n * 64 + l15;
#pragma unroll
      for (int r = 0; r < 4; ++r) cp[(size_t)r * N] = acc[j][n][r];
    }
  }
#undef SA_
#undef SB_
}

// ------------------------------------------------------------- flash attention
__global__ __launch_bounds__(256, 4) void attn_kernel(const hbf16* __restrict__ Q,
                                                      const hbf16* __restrict__ Kr,
                                                      const hbf16* __restrict__ Vt,
                                                      hbf16* __restrict__ O) {
  __shared__ __align__(16) hbf16 sK[64 * 128];  // [key][d], chunk^(key&15) swizzle
  __shared__ __align__(16) hbf16 sV[128 * 64];  // [d][key], chunk^(d&7) swizzle
  const int tid = threadIdx.x;
  const int wave = tid >> 6, lane = tid & 63;
  const int l15 = lane & 15, quad = lane >> 4;
  const int bid = blockIdx.x;
  const int h = bid >> 5;
  const int qb = (31 - (bid & 31) + 8 * ((bid >> 8) & 3)) & 31;
  const int g = h >> 2;
  const int qrow0 = qb * 64 + wave * 16;
  const int qrow = qrow0 + l15;

  bf16x8 qf[4];
  {
    const hbf16* qp = Q + (size_t)qrow * 4096 + h * 128 + quad * 8;
#pragma unroll
    for (int kc = 0; kc < 4; ++kc) qf[kc] = *(const bf16x8*)(qp + kc * 32);
  }
  f32x4 of[8];
#pragma unroll
  for (int nf = 0; nf < 8; ++nf) of[nf] = (f32x4){0.f, 0.f, 0.f, 0.f};
  float m_i = -1e30f, l_i = 0.f;

  const char* Kb = (const char*)Kr + (size_t)g * 256;
  const char* Vb = (const char*)Vt + (size_t)g * 524288;
  char* sKb = (char*)sK;
  char* sVb = (char*)sV;

  const int nkb = qb + 1;
  for (int kb = 0; kb < nkb; ++kb) {
#pragma unroll
    for (int r = 0; r < 4; ++r) {
      int f = r * 4096 + tid * 16;
      {
        int row = f >> 8;
        int lc = ((f >> 4) & 15) ^ (row & 15);
        ASYNC16(sKb + f, Kb + (size_t)(kb * 64 + row) * 2048 + lc * 16);
      }
      {
        int row = f >> 7;
        int lc = ((f >> 4) & 7) ^ (row & 7);
        ASYNC16(sVb + f, Vb + (size_t)row * 4096 + kb * 128 + lc * 16);
      }
    }
    __syncthreads();

    f32x4 sacc[4];
#pragma unroll
    for (int n = 0; n < 4; ++n) sacc[n] = (f32x4){0.f, 0.f, 0.f, 0.f};
#pragma unroll
    for (int n = 0; n < 4; ++n)
#pragma unroll
      for (int kc = 0; kc < 4; ++kc) {
        bf16x8 kf = *(const bf16x8*)(sKb + (n * 16 + l15) * 256 +
                                     (((kc << 2) | quad) ^ l15) * 16);
        sacc[n] = MFMA16(kf, qf[kc], sacc[n]);
      }

    float p[4][4];
    float mx = -1e30f;
    if (kb == qb) {
      const int key0 = kb * 64 + quad * 4;
#pragma unroll
      for (int n = 0; n < 4; ++n)
#pragma unroll
        for (int r = 0; r < 4; ++r) {
          float s = sacc[n][r];
          s = (key0 + n * 16 + r > qrow) ? -1e30f : s;
          p[n][r] = s;
          mx = fmaxf(mx, s);
        }
    } else {
#pragma unroll
      for (int n = 0; n < 4; ++n)
#pragma unroll
        for (int r = 0; r < 4; ++r) {
          p[n][r] = sacc[n][r];
          mx = fmaxf(mx, sacc[n][r]);
        }
    }
    mx = fmaxf(mx, __shfl_xor(mx, 16, 64));
    mx = fmaxf(mx, __shfl_xor(mx, 32, 64));
    float mnew = fmaxf(m_i, mx);
    float alpha = fexp2(m_i - mnew);
    m_i = mnew;
    float sum = 0.f;
#pragma unroll
    for (int n = 0; n < 4; ++n)
#pragma unroll
      for (int r = 0; r < 4; ++r) {
        p[n][r] = fexp2(p[n][r] - mnew);
        sum += p[n][r];
      }
    sum += __shfl_xor(sum, 16, 64);
    sum += __shfl_xor(sum, 32, 64);
    l_i = l_i * alpha + sum;
#pragma unroll
    for (int nf = 0; nf < 8; ++nf)
#pragma unroll
      for (int r = 0; r < 4; ++r) of[nf][r] *= alpha;

    unsigned pk[8];
#pragma unroll
    for (int n = 0; n < 4; ++n)
#pragma unroll
      for (int h2 = 0; h2 < 2; ++h2) {
        hbf16 t2[2] = {__float2bfloat16(p[n][2 * h2]), __float2bfloat16(p[n][2 * h2 + 1])};
        pk[n * 2 + h2] = *(unsigned*)t2;
      }

    const int sa = ((quad & 1) << 5) + l15;
    const int sb2 = sa + 16;
#pragma unroll
    for (int kc = 0; kc < 2; ++kc) {
      unsigned a0 = __shfl((int)pk[kc * 4 + 0], sa, 64);
      unsigned a1 = __shfl((int)pk[kc * 4 + 1], sa, 64);
      unsigned a2 = __shfl((int)pk[kc * 4 + 2], sa, 64);
      unsigned a3 = __shfl((int)pk[kc * 4 + 3], sa, 64);
      unsigned b0 = __shfl((int)pk[kc * 4 + 0], sb2, 64);
      unsigned b1 = __shfl((int)pk[kc * 4 + 1], sb2, 64);
      unsigned b2 = __shfl((int)pk[kc * 4 + 2], sb2, 64);
      unsigned b3 = __shfl((int)pk[kc * 4 + 3], sb2, 64);
      union {
        unsigned u[4];
        bf16x8 v;
      } pf;
      pf.u[0] = (quad < 2) ? a0 : a2;
      pf.u[1] = (quad < 2) ? a1 : a3;
      pf.u[2] = (quad < 2) ? b0 : b2;
      pf.u[3] = (quad < 2) ? b1 : b3;
#pragma unroll
      for (int nf = 0; nf < 8; ++nf) {
        bf16x8 vf = *(const bf16x8*)(sVb + (nf * 16 + l15) * 128 +
                                     (((kc << 2) | quad) ^ (l15 & 7)) * 16);
        of[nf] = MFMA16(vf, pf.v, of[nf]);
      }
    }
    __syncthreads();
  }

  const float invl = 1.f / l_i;
#pragma unroll
  for (int nf = 0; nf < 8; ++nf) {
    hbf16 t4[4];
#pragma unroll
    for (int r = 0; r < 4; ++r) t4[r] = __float2bfloat16(of[nf][r] * invl);
    *(uint2*)(O + (size_t)qrow * 4096 + h * 128 + nf * 16 + quad * 4) = *(uint2*)t4;
  }
}

// ---------------------------------------------------------------------- launch
extern "C" void kernel_launch(void* const* d_in, const int* in_sizes, int n_in,
                              void* d_out, int out_size, void* d_ws, size_t ws_size,
                              hipStream_t stream) {
  const float* x = (const float*)d_in[0];
  const float* wq = (const float*)d_in[1];
  const float* wk = (const float*)d_in[2];
  const float* wv = (const float*)d_in[3];
  const float* wo = (const float*)d_in[4];
  const float* fc = (const float*)d_in[5];
  const float* fs = (const float*)d_in[6];
  float* out = (float*)d_out;

  char* w = (char*)d_ws;
  size_t off = 0;
  auto alloc = [&](size_t bytes) -> char* {
    char* p = w + off;
    off += (bytes + 255) & ~(size_t)255;
    return p;
  };
  unsigned int* gmaxs = (unsigned int*)alloc(256 * 8 * 4);
  hbf16* xb = (hbf16*)alloc((size_t)2048 * 4096 * 2);
  hbf16* wqkv = (hbf16*)alloc((size_t)6144 * 4096 * 2);  // stacked wq_q/wk_q/wv_q; later wo_q
  float* qkv = (float*)alloc((size_t)2048 * 6144 * 4);   // fused proj out; later attn_out (bf16)
  hbf16* qrope = (hbf16*)alloc((size_t)2048 * 4096 * 2);
  hbf16* krope = (hbf16*)alloc((size_t)2048 * 1024 * 2);
  hbf16* vt = (hbf16*)alloc((size_t)8 * 128 * 2048 * 2);
  hbf16* woq = wqkv;           // reused after QKV GEMM consumes wqkv
  hbf16* attno = (hbf16*)qkv;  // reused after rope/transpose consume qkv

  const float kSc = 0.12753139668280277f;  // (1/sqrt(128)) * log2(e)

  quant_max_kernel<<<dim3(512, 4), 256, 0, stream>>>(wq, wk, wv, wo, gmaxs);
  prep_kernel<<<dim3(2048, 4), 256, 0, stream>>>(wq, wk, wv, x, wqkv, xb, gmaxs);
  gemm_tp_kernel<6><<<dim3(16, 16), 512, 0, stream>>>(xb, wqkv, qkv, 6144);
  postproc_kernel<<<23040, 256, 0, stream>>>(wo, woq, gmaxs, qkv, fc, fs, qrope, krope, vt, kSc);
  attn_kernel<<<1024, 256, 0, stream>>>(qrope, krope, vt, attno);
  gemm_tp_kernel<4><<<dim3(16, 16), 512, 0, stream>>>(attno, woq, out, 4096);
  (void)in_sizes; (void)n_in; (void)out_size; (void)ws_size;
}